// Round 1
// baseline (309.082 us; speedup 1.0000x reference)
//
#include <hip/hip_runtime.h>

// Problem constants (from reference setup_inputs):
//   B=8192 batch, F=128 fields (entmax axis), E=64 emb, O=64 heads
// out[b,o,f] = entmax_1.5(0.5 * x[b] @ Q^T)[o,f] * values[o,f]
// Reference runs 50 bisection iters in fp32; dm = 0.9116/2^n < ulp(tau)
// after ~26 iters, so 26 iterations are fp32-converged (|dtau| <= 1.4e-8,
// |dout| <= ~6e-8, threshold is 5e-3).

#define NITER 26

constexpr int Bn = 8192;
constexpr int Fn = 128;
constexpr int En = 64;
constexpr int On = 64;

__global__ __launch_bounds__(256) void sparse_att_entmax_kernel(
    const float* __restrict__ x,      // (B,F,E)
    const float* __restrict__ Qm,     // (O,E)
    const float* __restrict__ vals,   // (O,F)
    float* __restrict__ out)          // (B,O,F)
{
  // x[b] staged in LDS; +1 float4 pad per 32-row group so the four
  // h-subgroups hit distinct bank quartets on the broadcast b128 reads.
  __shared__ float xs[Fn * En + 16];

  const int b   = blockIdx.x;
  const int tid = threadIdx.x;

  // ---- Stage x[b] (128x64 fp32 = 32 KiB) into LDS, coalesced ----
  {
    const float4* xg = (const float4*)(x + (size_t)b * (Fn * En));
    #pragma unroll
    for (int k = 0; k < 8; ++k) {
      int j = tid + k * 256;          // linear float4 index 0..2047
      int f = j >> 4;                 // row (16 float4 per row)
      int c = j & 15;
      ((float4*)xs)[f * 16 + (f >> 5) + c] = xg[j];
    }
  }

  const int o = tid >> 2;             // 0..63 : output head (entmax row)
  const int h = tid & 3;              // 0..3  : quarter of the F=128 row

  // ---- Q[o] row into registers (L1/L2-cached global reads) ----
  float q[En];
  {
    const float4* qg = (const float4*)(Qm + o * En);
    #pragma unroll
    for (int k = 0; k < 16; ++k) {
      float4 v = qg[k];
      q[4*k+0] = v.x; q[4*k+1] = v.y; q[4*k+2] = v.z; q[4*k+3] = v.w;
    }
  }
  __syncthreads();

  // ---- GEMM: att[fi] = 0.5 * dot(x[b, h*32+fi, :], Q[o, :]) ----
  // (0.5 = alpha-1 folded in: Xs = (alpha-1) * att_gates)
  float att[32];
  const float* xbase = xs + (h * 32) * En + h * 4;   // padded row base
  #pragma unroll
  for (int fi = 0; fi < 32; ++fi) {
    const float* xrow = xbase + fi * En;
    float a0 = 0.f, a1 = 0.f, a2 = 0.f, a3 = 0.f;
    #pragma unroll
    for (int e = 0; e < En; e += 4) {
      float4 xv = *(const float4*)(xrow + e);
      a0 = fmaf(xv.x, q[e+0], a0);
      a1 = fmaf(xv.y, q[e+1], a1);
      a2 = fmaf(xv.z, q[e+2], a2);
      a3 = fmaf(xv.w, q[e+3], a3);
    }
    att[fi] = ((a0 + a1) + (a2 + a3)) * 0.5f;
  }

  // ---- row max across the 4 lanes owning this (b,o) row ----
  float m = att[0];
  #pragma unroll
  for (int i = 1; i < 32; ++i) m = fmaxf(m, att[i]);
  m = fmaxf(m, __shfl_xor(m, 1));
  m = fmaxf(m, __shfl_xor(m, 2));

  // ---- bisection on tau (entmax-1.5: p = relu(Xs - tau)^2) ----
  float tau_lo = m - 1.0f;
  float dm     = 0.91161165235168155f;   // 1 - (1/128)^0.5
  float tau_m  = tau_lo;
  float ssum   = 1.0f;

  for (int it = 0; it < NITER; ++it) {
    dm *= 0.5f;
    tau_m = tau_lo + dm;
    float s0 = 0.f, s1 = 0.f, s2 = 0.f, s3 = 0.f;
    #pragma unroll
    for (int i = 0; i < 32; i += 4) {
      float t0 = fmaxf(att[i+0] - tau_m, 0.0f);
      float t1 = fmaxf(att[i+1] - tau_m, 0.0f);
      float t2 = fmaxf(att[i+2] - tau_m, 0.0f);
      float t3 = fmaxf(att[i+3] - tau_m, 0.0f);
      s0 = fmaf(t0, t0, s0);
      s1 = fmaf(t1, t1, s1);
      s2 = fmaf(t2, t2, s2);
      s3 = fmaf(t3, t3, s3);
    }
    float s = (s0 + s1) + (s2 + s3);
    s += __shfl_xor(s, 1);
    s += __shfl_xor(s, 2);
    ssum = s;                                // sum(p_m) of this iter
    tau_lo = (s >= 1.0f) ? tau_m : tau_lo;   // f_m >= 0 accepts midpoint
  }

  // ---- final: p at last tau_m, renorm by last sum, scale by values ----
  float inv = 1.0f / ssum;
  const float4* vg = (const float4*)(vals + o * Fn + h * 32);
  float4* og = (float4*)(out + ((size_t)b * On + o) * Fn + h * 32);
  #pragma unroll
  for (int i = 0; i < 32; i += 4) {
    float4 vv = vg[i / 4];
    float t0 = fmaxf(att[i+0] - tau_m, 0.0f);
    float t1 = fmaxf(att[i+1] - tau_m, 0.0f);
    float t2 = fmaxf(att[i+2] - tau_m, 0.0f);
    float t3 = fmaxf(att[i+3] - tau_m, 0.0f);
    float4 r;
    r.x = t0 * t0 * inv * vv.x;
    r.y = t1 * t1 * inv * vv.y;
    r.z = t2 * t2 * inv * vv.z;
    r.w = t3 * t3 * inv * vv.w;
    og[i / 4] = r;
  }
}

extern "C" void kernel_launch(void* const* d_in, const int* in_sizes, int n_in,
                              void* d_out, int out_size, void* d_ws, size_t ws_size,
                              hipStream_t stream) {
  const float* x  = (const float*)d_in[0];
  const float* Qm = (const float*)d_in[1];
  const float* v  = (const float*)d_in[2];
  float* out = (float*)d_out;
  hipLaunchKernelGGL(sparse_att_entmax_kernel, dim3(Bn), dim3(256), 0, stream,
                     x, Qm, v, out);
}

// Round 2
// 134.925 us; speedup vs baseline: 2.2908x; 2.2908x over previous
//
#include <hip/hip_runtime.h>

// out[b,o,f] = entmax_1.5(0.5 * x[b] @ Q^T)[o,f] * values[o,f]
// B=8192, F=128 (entmax axis), E=64, O=64, fp32 in/out.
//
// R2: GEMM via fp16 split-precision MFMA (x = hi+lo, Q = hi+lo, 3 products
// hi*hi + hi*lo + lo*hi -> att err ~1e-5). Solver: 6 bisection + 4 Newton
// (f(tau) = sum relu(Xs-tau)^2 - 1 is convex decreasing; Newton from the
// f>=0 side converges monotonically), final renorm matches reference.

typedef __attribute__((ext_vector_type(8))) _Float16 half8;
typedef __attribute__((ext_vector_type(4))) float floatx4;

constexpr int Bn = 8192;

#define NBIS 6
#define NNEWT 4

// ---- pre-kernel: Q (64x64 f32) -> fp16 hi/lo in workspace ----
__global__ void convert_q_kernel(const float* __restrict__ Qf,
                                 _Float16* __restrict__ Qh,
                                 _Float16* __restrict__ Ql) {
  int i = blockIdx.x * 256 + threadIdx.x;   // 4096 elements
  float q = Qf[i];
  _Float16 h = (_Float16)q;
  float r = q - (float)h;
  Qh[i] = h;
  Ql[i] = (_Float16)r;
}

__device__ inline unsigned pk2(_Float16 a, _Float16 b) {
  union { _Float16 h[2]; unsigned u; } p;
  p.h[0] = a; p.h[1] = b;
  return p.u;
}

__global__ __launch_bounds__(256, 4) void sparse_att_kernel(
    const float* __restrict__ x,      // (B,128,64)
    const _Float16* __restrict__ Qh,  // (64,64) fp16 hi
    const _Float16* __restrict__ Ql,  // (64,64) fp16 lo
    const float* __restrict__ vals,   // (64,128)
    float* __restrict__ out)          // (B,64,128)
{
  // x[b] as fp16 hi/lo, 16B blocks XOR-swizzled by (f&7) so MFMA fragment
  // reads (16 lanes at row-stride 128B) are 2-way (free) instead of 16-way.
  __shared__ _Float16 xh[128 * 64];
  __shared__ _Float16 xl[128 * 64];

  const int b   = blockIdx.x;
  const int tid = threadIdx.x;
  const int l   = tid & 63;
  const int otile = tid >> 6;         // wave id 0..3 -> o-tile
  const int lc  = l & 15;             // A-row within tile / C-col (o)
  const int fq  = l >> 4;             // k-block selector / C row-quad
  const int o   = otile * 16 + lc;    // this lane's output o (C layout)

  // ---- B fragments (Q hi/lo) straight from global (L2-hot, 16KB) ----
  // B layout: lane holds B[k = fq*8..+7][n = lc]; with B = Q^T that is
  // Qh[o][k] row-major -> natural 16B loads.
  half8 bh0 = *(const half8*)(Qh + o * 64 + 0 * 32 + fq * 8);
  half8 bh1 = *(const half8*)(Qh + o * 64 + 1 * 32 + fq * 8);
  half8 bl0 = *(const half8*)(Ql + o * 64 + 0 * 32 + fq * 8);
  half8 bl1 = *(const half8*)(Ql + o * 64 + 1 * 32 + fq * 8);

  // ---- stage x[b] -> LDS fp16 hi/lo, swizzled ----
  {
    const float4* xg = (const float4*)(x + (size_t)b * 8192);
    #pragma unroll
    for (int k = 0; k < 8; ++k) {
      int j = tid + k * 256;          // float4 index 0..2047
      int f = j >> 4, c = j & 15;
      float4 v = xg[j];
      _Float16 h0 = (_Float16)v.x, h1 = (_Float16)v.y,
               h2 = (_Float16)v.z, h3 = (_Float16)v.w;
      float r0 = v.x - (float)h0, r1 = v.y - (float)h1,
            r2 = v.z - (float)h2, r3 = v.w - (float)h3;
      int byteoff = f * 128 + (((c >> 1) ^ (f & 7)) * 16) + (c & 1) * 8;
      uint2 uh; uh.x = pk2(h0, h1); uh.y = pk2(h2, h3);
      uint2 ul; ul.x = pk2((_Float16)r0, (_Float16)r1);
                ul.y = pk2((_Float16)r2, (_Float16)r3);
      *(uint2*)((char*)xh + byteoff) = uh;
      *(uint2*)((char*)xl + byteoff) = ul;
    }
  }
  __syncthreads();

  // ---- GEMM: C[f][o] tiles via mfma_f32_16x16x32_f16, 3-product split ----
  floatx4 acc[8];
  #pragma unroll
  for (int t = 0; t < 8; ++t) acc[t] = (floatx4)0.0f;

  #pragma unroll
  for (int ks = 0; ks < 2; ++ks) {
    half8 bh = ks ? bh1 : bh0;
    half8 bl = ks ? bl1 : bl0;
    #pragma unroll
    for (int ft = 0; ft < 8; ++ft) {
      int f = ft * 16 + lc;                    // A-row for this lane
      int blk = (ks * 4 + fq) ^ (f & 7);
      int byteoff = f * 128 + blk * 16;
      half8 ah = *(const half8*)((const char*)xh + byteoff);
      half8 al = *(const half8*)((const char*)xl + byteoff);
      acc[ft] = __builtin_amdgcn_mfma_f32_16x16x32_f16(ah, bh, acc[ft], 0, 0, 0);
      acc[ft] = __builtin_amdgcn_mfma_f32_16x16x32_f16(ah, bl, acc[ft], 0, 0, 0);
      acc[ft] = __builtin_amdgcn_mfma_f32_16x16x32_f16(al, bh, acc[ft], 0, 0, 0);
    }
  }

  // ---- att = Xs = 0.5 * att_gates; lane holds f = ft*16 + fq*4 + reg ----
  float att[32];
  #pragma unroll
  for (int t = 0; t < 8; ++t) {
    att[t * 4 + 0] = acc[t][0] * 0.5f;
    att[t * 4 + 1] = acc[t][1] * 0.5f;
    att[t * 4 + 2] = acc[t][2] * 0.5f;
    att[t * 4 + 3] = acc[t][3] * 0.5f;
  }

  // ---- row max over 128 f (4 lanes: xor 16, 32) ----
  float m = att[0];
  #pragma unroll
  for (int i = 1; i < 32; ++i) m = fmaxf(m, att[i]);
  m = fmaxf(m, __shfl_xor(m, 16));
  m = fmaxf(m, __shfl_xor(m, 32));

  // ---- bisection (keeps f(tau) >= 0 invariant) ----
  float tau = m - 1.0f;
  float dm  = 0.91161165235168155f;       // 1 - (1/128)^0.5
  #pragma unroll
  for (int it = 0; it < NBIS; ++it) {
    dm *= 0.5f;
    float tm = tau + dm;
    float s0 = 0.f, s1 = 0.f, s2 = 0.f, s3 = 0.f;
    #pragma unroll
    for (int i = 0; i < 32; i += 4) {
      float t0 = fmaxf(att[i + 0] - tm, 0.0f);
      float t1 = fmaxf(att[i + 1] - tm, 0.0f);
      float t2 = fmaxf(att[i + 2] - tm, 0.0f);
      float t3 = fmaxf(att[i + 3] - tm, 0.0f);
      s0 = fmaf(t0, t0, s0); s1 = fmaf(t1, t1, s1);
      s2 = fmaf(t2, t2, s2); s3 = fmaf(t3, t3, s3);
    }
    float s = (s0 + s1) + (s2 + s3);
    s += __shfl_xor(s, 16);
    s += __shfl_xor(s, 32);
    tau = (s >= 1.0f) ? tm : tau;
  }

  // ---- Newton (monotone from f>=0 side; d = sum relu >= 1 here) ----
  #pragma unroll
  for (int it = 0; it < NNEWT; ++it) {
    float s0 = 0.f, s1 = 0.f, d0 = 0.f, d1 = 0.f;
    #pragma unroll
    for (int i = 0; i < 32; i += 2) {
      float t0 = fmaxf(att[i + 0] - tau, 0.0f);
      float t1 = fmaxf(att[i + 1] - tau, 0.0f);
      s0 = fmaf(t0, t0, s0); d0 += t0;
      s1 = fmaf(t1, t1, s1); d1 += t1;
    }
    float s = s0 + s1, d = d0 + d1;
    s += __shfl_xor(s, 16);  d += __shfl_xor(d, 16);
    s += __shfl_xor(s, 32);  d += __shfl_xor(d, 32);
    tau += (s - 1.0f) / (2.0f * d);
  }

  // ---- final p, renorm (matches reference's p_m / sum(p_m)) ----
  float s0 = 0.f, s1 = 0.f;
  #pragma unroll
  for (int i = 0; i < 32; ++i) {
    float t = fmaxf(att[i] - tau, 0.0f);
    float p = t * t;
    att[i] = p;
    if (i & 1) s1 += p; else s0 += p;
  }
  float s = s0 + s1;
  s += __shfl_xor(s, 16);
  s += __shfl_xor(s, 32);
  float inv = 1.0f / s;

  const float4* vg = (const float4*)(vals + o * 128 + fq * 4);
  float4* og = (float4*)(out + ((size_t)b * 64 + o) * 128 + fq * 4);
  #pragma unroll
  for (int ft = 0; ft < 8; ++ft) {
    float4 vv = vg[ft * 4];              // stride 16 floats
    float4 r;
    r.x = att[ft * 4 + 0] * inv * vv.x;
    r.y = att[ft * 4 + 1] * inv * vv.y;
    r.z = att[ft * 4 + 2] * inv * vv.z;
    r.w = att[ft * 4 + 3] * inv * vv.w;
    og[ft * 4] = r;
  }
}

extern "C" void kernel_launch(void* const* d_in, const int* in_sizes, int n_in,
                              void* d_out, int out_size, void* d_ws, size_t ws_size,
                              hipStream_t stream) {
  const float* x  = (const float*)d_in[0];
  const float* Qf = (const float*)d_in[1];
  const float* v  = (const float*)d_in[2];
  float* out = (float*)d_out;

  _Float16* Qh = (_Float16*)d_ws;            // 4096 halves = 8KB
  _Float16* Ql = Qh + 4096;                  // next 8KB

  hipLaunchKernelGGL(convert_q_kernel, dim3(16), dim3(256), 0, stream, Qf, Qh, Ql);
  hipLaunchKernelGGL(sparse_att_kernel, dim3(Bn), dim3(256), 0, stream,
                     x, Qh, Ql, v, out);
}

// Round 4
// 118.140 us; speedup vs baseline: 2.6162x; 1.1421x over previous
//
#include <hip/hip_runtime.h>

// out[b,o,f] = entmax_1.5(0.5 * x[b] @ Q^T)[o,f] * values[o,f]
// B=8192, F=128 (entmax axis), E=64, O=64, fp32 in/out.
//
// R4 (= R3 + compile fix): fp16 MFMA GEMM with 2-product split
// (x_hi*Q_hi + x_hi*Q_lo; x's own fp16 rounding ~3e-4 on att is inside the
// 5e-3 budget). x staged hi-only -> 16 KB LDS, 5 blocks/CU. Solver:
// 5 bisection + 4 Newton, accumulator registers reused as the solver array.
// Nontemporal output stores (via ext_vector_type, the HIP float4 struct is
// rejected by the builtin) keep L3 free for the x read stream.

typedef __attribute__((ext_vector_type(8))) _Float16 half8;
typedef __attribute__((ext_vector_type(4))) float floatx4;

constexpr int Bn = 8192;

#define NBIS 5
#define NNEWT 4

// ---- pre-kernel: Q (64x64 f32) -> fp16 hi/lo in workspace ----
__global__ void convert_q_kernel(const float* __restrict__ Qf,
                                 _Float16* __restrict__ Qh,
                                 _Float16* __restrict__ Ql) {
  int i = blockIdx.x * 256 + threadIdx.x;   // 4096 elements
  float q = Qf[i];
  _Float16 h = (_Float16)q;
  float r = q - (float)h;
  Qh[i] = h;
  Ql[i] = (_Float16)r;
}

__device__ inline unsigned pk2(_Float16 a, _Float16 b) {
  union { _Float16 h[2]; unsigned u; } p;
  p.h[0] = a; p.h[1] = b;
  return p.u;
}

__global__ __launch_bounds__(256, 5) void sparse_att_kernel(
    const float* __restrict__ x,      // (B,128,64)
    const _Float16* __restrict__ Qh,  // (64,64) fp16 hi
    const _Float16* __restrict__ Ql,  // (64,64) fp16 lo
    const float* __restrict__ vals,   // (64,128)
    float* __restrict__ out)          // (B,64,128)
{
  // x[b] as fp16 (hi only), 16B blocks XOR-swizzled by (f&7) so MFMA
  // fragment reads (16 lanes at row-stride 128B) are 2-way (free).
  __shared__ _Float16 xh[128 * 64];

  const int b   = blockIdx.x;
  const int tid = threadIdx.x;
  const int l   = tid & 63;
  const int otile = tid >> 6;         // wave id 0..3 -> o-tile
  const int lc  = l & 15;             // A-row within tile / C-col (o)
  const int fq  = l >> 4;             // k-block selector / C row-quad
  const int o   = otile * 16 + lc;    // this lane's output o (C layout)

  // ---- stage x[b] -> LDS fp16 hi, swizzled ----
  {
    const float4* xg = (const float4*)(x + (size_t)b * 8192);
    #pragma unroll
    for (int k = 0; k < 8; ++k) {
      int j = tid + k * 256;          // float4 index 0..2047
      int f = j >> 4, c = j & 15;
      float4 v = xg[j];
      _Float16 h0 = (_Float16)v.x, h1 = (_Float16)v.y,
               h2 = (_Float16)v.z, h3 = (_Float16)v.w;
      int byteoff = f * 128 + (((c >> 1) ^ (f & 7)) * 16) + (c & 1) * 8;
      uint2 uh; uh.x = pk2(h0, h1); uh.y = pk2(h2, h3);
      *(uint2*)((char*)xh + byteoff) = uh;
    }
  }

  // ---- B fragments (Q hi/lo) straight from global (L2-hot, 16KB) ----
  // B layout: lane holds B[k = fq*8..+7][n = lc]; with B = Q^T that is
  // Qh[o][k] row-major -> natural 16B loads.
  half8 bh0 = *(const half8*)(Qh + o * 64 + 0 * 32 + fq * 8);
  half8 bh1 = *(const half8*)(Qh + o * 64 + 1 * 32 + fq * 8);
  half8 bl0 = *(const half8*)(Ql + o * 64 + 0 * 32 + fq * 8);
  half8 bl1 = *(const half8*)(Ql + o * 64 + 1 * 32 + fq * 8);

  __syncthreads();

  // ---- GEMM: C[f][o] tiles via mfma_f32_16x16x32_f16, 2-product split ----
  floatx4 acc[8];
  #pragma unroll
  for (int t = 0; t < 8; ++t) acc[t] = (floatx4)0.0f;

  #pragma unroll
  for (int ks = 0; ks < 2; ++ks) {
    half8 bh = ks ? bh1 : bh0;
    half8 bl = ks ? bl1 : bl0;
    #pragma unroll
    for (int ft = 0; ft < 8; ++ft) {
      int f = ft * 16 + lc;                    // A-row for this lane
      int blk = (ks * 4 + fq) ^ (f & 7);
      int byteoff = f * 128 + blk * 16;
      half8 ah = *(const half8*)((const char*)xh + byteoff);
      acc[ft] = __builtin_amdgcn_mfma_f32_16x16x32_f16(ah, bh, acc[ft], 0, 0, 0);
      acc[ft] = __builtin_amdgcn_mfma_f32_16x16x32_f16(ah, bl, acc[ft], 0, 0, 0);
    }
  }

  // ---- att = Xs = 0.5 * att_gates, in place over acc ----
  // lane's f for acc[t][j] is ft*16 + fq*4 + j
  #pragma unroll
  for (int t = 0; t < 8; ++t) acc[t] *= 0.5f;
  float* att = (float*)acc;                    // 32 floats, static indexing

  // ---- row max over 128 f (4 lanes: xor 16, 32) ----
  float m = att[0];
  #pragma unroll
  for (int i = 1; i < 32; ++i) m = fmaxf(m, att[i]);
  m = fmaxf(m, __shfl_xor(m, 16));
  m = fmaxf(m, __shfl_xor(m, 32));

  // ---- bisection (keeps f(tau) >= 0 invariant) ----
  float tau = m - 1.0f;
  float dm  = 0.91161165235168155f;       // 1 - (1/128)^0.5
  #pragma unroll
  for (int it = 0; it < NBIS; ++it) {
    dm *= 0.5f;
    float tm = tau + dm;
    float s0 = 0.f, s1 = 0.f, s2 = 0.f, s3 = 0.f;
    #pragma unroll
    for (int i = 0; i < 32; i += 4) {
      float t0 = fmaxf(att[i + 0] - tm, 0.0f);
      float t1 = fmaxf(att[i + 1] - tm, 0.0f);
      float t2 = fmaxf(att[i + 2] - tm, 0.0f);
      float t3 = fmaxf(att[i + 3] - tm, 0.0f);
      s0 = fmaf(t0, t0, s0); s1 = fmaf(t1, t1, s1);
      s2 = fmaf(t2, t2, s2); s3 = fmaf(t3, t3, s3);
    }
    float s = (s0 + s1) + (s2 + s3);
    s += __shfl_xor(s, 16);
    s += __shfl_xor(s, 32);
    tau = (s >= 1.0f) ? tm : tau;
  }

  // ---- Newton (monotone from f>=0 side; d = sum relu > 0 here) ----
  #pragma unroll
  for (int it = 0; it < NNEWT; ++it) {
    float s0 = 0.f, s1 = 0.f, d0 = 0.f, d1 = 0.f;
    #pragma unroll
    for (int i = 0; i < 32; i += 2) {
      float t0 = fmaxf(att[i + 0] - tau, 0.0f);
      float t1 = fmaxf(att[i + 1] - tau, 0.0f);
      s0 = fmaf(t0, t0, s0); d0 += t0;
      s1 = fmaf(t1, t1, s1); d1 += t1;
    }
    float s = s0 + s1, d = d0 + d1;
    s += __shfl_xor(s, 16);  d += __shfl_xor(d, 16);
    s += __shfl_xor(s, 32);  d += __shfl_xor(d, 32);
    tau += (s - 1.0f) / (2.0f * d);
  }

  // ---- final p, renorm (matches reference's p_m / sum(p_m)) ----
  float s0 = 0.f, s1 = 0.f;
  #pragma unroll
  for (int i = 0; i < 32; ++i) {
    float t = fmaxf(att[i] - tau, 0.0f);
    float p = t * t;
    att[i] = p;
    if (i & 1) s1 += p; else s0 += p;
  }
  float s = s0 + s1;
  s += __shfl_xor(s, 16);
  s += __shfl_xor(s, 32);
  float inv = 1.0f / s;

  const float4* vg = (const float4*)(vals + o * 128 + fq * 4);
  floatx4* og = (floatx4*)(out + ((size_t)b * 64 + o) * 128 + fq * 4);
  #pragma unroll
  for (int ft = 0; ft < 8; ++ft) {
    float4 vv = vg[ft * 4];              // stride 16 floats
    floatx4 r;
    r.x = att[ft * 4 + 0] * inv * vv.x;
    r.y = att[ft * 4 + 1] * inv * vv.y;
    r.z = att[ft * 4 + 2] * inv * vv.z;
    r.w = att[ft * 4 + 3] * inv * vv.w;
    __builtin_nontemporal_store(r, &og[ft * 4]);
  }
}

extern "C" void kernel_launch(void* const* d_in, const int* in_sizes, int n_in,
                              void* d_out, int out_size, void* d_ws, size_t ws_size,
                              hipStream_t stream) {
  const float* x  = (const float*)d_in[0];
  const float* Qf = (const float*)d_in[1];
  const float* v  = (const float*)d_in[2];
  float* out = (float*)d_out;

  _Float16* Qh = (_Float16*)d_ws;            // 4096 halves = 8KB
  _Float16* Ql = Qh + 4096;                  // next 8KB

  hipLaunchKernelGGL(convert_q_kernel, dim3(16), dim3(256), 0, stream, Qf, Qh, Ql);
  hipLaunchKernelGGL(sparse_att_kernel, dim3(Bn), dim3(256), 0, stream,
                     x, Qh, Ql, v, out);
}

// Round 5
// 114.217 us; speedup vs baseline: 2.7061x; 1.0344x over previous
//
#include <hip/hip_runtime.h>

// out[b,o,f] = entmax_1.5(0.5 * x[b] @ Q^T)[o,f] * values[o,f]
// B=8192, F=128 (entmax axis), E=64, O=64, fp32 in/out.
//
// R5: = R4 + (a) 8 blocks/CU (VGPR=36, LDS 16KB -> fits; 100% occupancy),
// (b) 0.5 folded into Q pre-conversion (exact pow2 scale in fp16),
// (c) Newton 4 -> 3. GEMM: fp16 MFMA, 2-product split
// (x_hi*Qh + x_hi*Ql), x staged hi-only in swizzled LDS. NT stores keep
// L3 for the x stream (R4: FETCH dropped to ~134MB of 268MB).

typedef __attribute__((ext_vector_type(8))) _Float16 half8;
typedef __attribute__((ext_vector_type(4))) float floatx4;

constexpr int Bn = 8192;

#define NBIS 5
#define NNEWT 3

// ---- pre-kernel: 0.5*Q (64x64 f32) -> fp16 hi/lo in workspace ----
__global__ void convert_q_kernel(const float* __restrict__ Qf,
                                 _Float16* __restrict__ Qh,
                                 _Float16* __restrict__ Ql) {
  int i = blockIdx.x * 256 + threadIdx.x;   // 4096 elements
  float q = Qf[i] * 0.5f;                   // fold alpha-1 here
  _Float16 h = (_Float16)q;
  float r = q - (float)h;
  Qh[i] = h;
  Ql[i] = (_Float16)r;
}

__device__ inline unsigned pk2(_Float16 a, _Float16 b) {
  union { _Float16 h[2]; unsigned u; } p;
  p.h[0] = a; p.h[1] = b;
  return p.u;
}

__global__ __launch_bounds__(256, 8) void sparse_att_kernel(
    const float* __restrict__ x,      // (B,128,64)
    const _Float16* __restrict__ Qh,  // (64,64) fp16 hi of 0.5*Q
    const _Float16* __restrict__ Ql,  // (64,64) fp16 lo of 0.5*Q
    const float* __restrict__ vals,   // (64,128)
    float* __restrict__ out)          // (B,64,128)
{
  // x[b] as fp16 (hi only), 16B blocks XOR-swizzled by (f&7) so MFMA
  // fragment reads (16 lanes at row-stride 128B) are 2-way (free).
  __shared__ _Float16 xh[128 * 64];

  const int b   = blockIdx.x;
  const int tid = threadIdx.x;
  const int l   = tid & 63;
  const int otile = tid >> 6;         // wave id 0..3 -> o-tile
  const int lc  = l & 15;             // A-row within tile / C-col (o)
  const int fq  = l >> 4;             // k-block selector / C row-quad
  const int o   = otile * 16 + lc;    // this lane's output o (C layout)

  // ---- stage x[b] -> LDS fp16 hi, swizzled ----
  {
    const float4* xg = (const float4*)(x + (size_t)b * 8192);
    #pragma unroll
    for (int k = 0; k < 8; ++k) {
      int j = tid + k * 256;          // float4 index 0..2047
      int f = j >> 4, c = j & 15;
      float4 v = xg[j];
      _Float16 h0 = (_Float16)v.x, h1 = (_Float16)v.y,
               h2 = (_Float16)v.z, h3 = (_Float16)v.w;
      int byteoff = f * 128 + (((c >> 1) ^ (f & 7)) * 16) + (c & 1) * 8;
      uint2 uh; uh.x = pk2(h0, h1); uh.y = pk2(h2, h3);
      *(uint2*)((char*)xh + byteoff) = uh;
    }
  }

  // ---- B fragments (0.5*Q hi/lo) straight from global (L2-hot, 16KB) ----
  // B layout: lane holds B[k = fq*8..+7][n = lc]; with B = Q^T that is
  // Qh[o][k] row-major -> natural 16B loads.
  half8 bh0 = *(const half8*)(Qh + o * 64 + 0 * 32 + fq * 8);
  half8 bh1 = *(const half8*)(Qh + o * 64 + 1 * 32 + fq * 8);
  half8 bl0 = *(const half8*)(Ql + o * 64 + 0 * 32 + fq * 8);
  half8 bl1 = *(const half8*)(Ql + o * 64 + 1 * 32 + fq * 8);

  __syncthreads();

  // ---- GEMM: C[f][o] tiles via mfma_f32_16x16x32_f16, 2-product split ----
  floatx4 acc[8];
  #pragma unroll
  for (int t = 0; t < 8; ++t) acc[t] = (floatx4)0.0f;

  #pragma unroll
  for (int ks = 0; ks < 2; ++ks) {
    half8 bh = ks ? bh1 : bh0;
    half8 bl = ks ? bl1 : bl0;
    #pragma unroll
    for (int ft = 0; ft < 8; ++ft) {
      int f = ft * 16 + lc;                    // A-row for this lane
      int blk = (ks * 4 + fq) ^ (f & 7);
      int byteoff = f * 128 + blk * 16;
      half8 ah = *(const half8*)((const char*)xh + byteoff);
      acc[ft] = __builtin_amdgcn_mfma_f32_16x16x32_f16(ah, bh, acc[ft], 0, 0, 0);
      acc[ft] = __builtin_amdgcn_mfma_f32_16x16x32_f16(ah, bl, acc[ft], 0, 0, 0);
    }
  }

  // ---- att = Xs (0.5 already folded into Q) ----
  // lane's f for acc[t][j] is ft*16 + fq*4 + j
  float* att = (float*)acc;                    // 32 floats, static indexing

  // ---- row max over 128 f (4 lanes: xor 16, 32) ----
  float m = att[0];
  #pragma unroll
  for (int i = 1; i < 32; ++i) m = fmaxf(m, att[i]);
  m = fmaxf(m, __shfl_xor(m, 16));
  m = fmaxf(m, __shfl_xor(m, 32));

  // ---- bisection (keeps f(tau) >= 0 invariant) ----
  float tau = m - 1.0f;
  float dm  = 0.91161165235168155f;       // 1 - (1/128)^0.5
  #pragma unroll
  for (int it = 0; it < NBIS; ++it) {
    dm *= 0.5f;
    float tm = tau + dm;
    float s0 = 0.f, s1 = 0.f, s2 = 0.f, s3 = 0.f;
    #pragma unroll
    for (int i = 0; i < 32; i += 4) {
      float t0 = fmaxf(att[i + 0] - tm, 0.0f);
      float t1 = fmaxf(att[i + 1] - tm, 0.0f);
      float t2 = fmaxf(att[i + 2] - tm, 0.0f);
      float t3 = fmaxf(att[i + 3] - tm, 0.0f);
      s0 = fmaf(t0, t0, s0); s1 = fmaf(t1, t1, s1);
      s2 = fmaf(t2, t2, s2); s3 = fmaf(t3, t3, s3);
    }
    float s = (s0 + s1) + (s2 + s3);
    s += __shfl_xor(s, 16);
    s += __shfl_xor(s, 32);
    tau = (s >= 1.0f) ? tm : tau;
  }

  // ---- Newton (monotone from f>=0 side; never overshoots: f convex) ----
  #pragma unroll
  for (int it = 0; it < NNEWT; ++it) {
    float s0 = 0.f, s1 = 0.f, d0 = 0.f, d1 = 0.f;
    #pragma unroll
    for (int i = 0; i < 32; i += 2) {
      float t0 = fmaxf(att[i + 0] - tau, 0.0f);
      float t1 = fmaxf(att[i + 1] - tau, 0.0f);
      s0 = fmaf(t0, t0, s0); d0 += t0;
      s1 = fmaf(t1, t1, s1); d1 += t1;
    }
    float s = s0 + s1, d = d0 + d1;
    s += __shfl_xor(s, 16);  d += __shfl_xor(d, 16);
    s += __shfl_xor(s, 32);  d += __shfl_xor(d, 32);
    tau += (s - 1.0f) / (2.0f * d);
  }

  // ---- final p, renorm (matches reference's p_m / sum(p_m)) ----
  float s0 = 0.f, s1 = 0.f;
  #pragma unroll
  for (int i = 0; i < 32; ++i) {
    float t = fmaxf(att[i] - tau, 0.0f);
    float p = t * t;
    att[i] = p;
    if (i & 1) s1 += p; else s0 += p;
  }
  float s = s0 + s1;
  s += __shfl_xor(s, 16);
  s += __shfl_xor(s, 32);
  float inv = 1.0f / s;

  const float4* vg = (const float4*)(vals + o * 128 + fq * 4);
  floatx4* og = (floatx4*)(out + ((size_t)b * 64 + o) * 128 + fq * 4);
  #pragma unroll
  for (int ft = 0; ft < 8; ++ft) {
    float4 vv = vg[ft * 4];              // stride 16 floats
    floatx4 r;
    r.x = att[ft * 4 + 0] * inv * vv.x;
    r.y = att[ft * 4 + 1] * inv * vv.y;
    r.z = att[ft * 4 + 2] * inv * vv.z;
    r.w = att[ft * 4 + 3] * inv * vv.w;
    __builtin_nontemporal_store(r, &og[ft * 4]);
  }
}

extern "C" void kernel_launch(void* const* d_in, const int* in_sizes, int n_in,
                              void* d_out, int out_size, void* d_ws, size_t ws_size,
                              hipStream_t stream) {
  const float* x  = (const float*)d_in[0];
  const float* Qf = (const float*)d_in[1];
  const float* v  = (const float*)d_in[2];
  float* out = (float*)d_out;

  _Float16* Qh = (_Float16*)d_ws;            // 4096 halves = 8KB
  _Float16* Ql = Qh + 4096;                  // next 8KB

  hipLaunchKernelGGL(convert_q_kernel, dim3(16), dim3(256), 0, stream, Qf, Qh, Ql);
  hipLaunchKernelGGL(sparse_att_kernel, dim3(Bn), dim3(256), 0, stream,
                     x, Qh, Ql, v, out);
}

// Round 6
// 94.550 us; speedup vs baseline: 3.2690x; 1.2080x over previous
//
#include <hip/hip_runtime.h>

// out[b,o,f] = entmax_1.5(0.5 * x[b] @ Q^T)[o,f] * values[o,f]
// B=8192, F=128 (entmax axis), E=64, O=64, fp32 in/out.
//
// R6: = R5 + coalesced output stores. The MFMA C-layout scatters each
// wave's output at 512B stride (16 disjoint 64B lines per store instr,
// NT-bypassed -> fragmented HBM bursts; R5 measured WRITE=356MB for a
// 268MB output). Fix: bounce the output through the dead 16KB x-tile LDS
// buffer in two 64x64-f32 passes; store with linear tid->addr mapping
// (256B contiguous chunks, full L2 sectors). XOR-swizzle (o&7)<<4 keeps
// LDS traffic conflict-free.

typedef __attribute__((ext_vector_type(8))) _Float16 half8;
typedef __attribute__((ext_vector_type(4))) float floatx4;

constexpr int Bn = 8192;

#define NBIS 5
#define NNEWT 3

// ---- pre-kernel: 0.5*Q (64x64 f32) -> fp16 hi/lo in workspace ----
__global__ void convert_q_kernel(const float* __restrict__ Qf,
                                 _Float16* __restrict__ Qh,
                                 _Float16* __restrict__ Ql) {
  int i = blockIdx.x * 256 + threadIdx.x;   // 4096 elements
  float q = Qf[i] * 0.5f;                   // fold alpha-1 here
  _Float16 h = (_Float16)q;
  float r = q - (float)h;
  Qh[i] = h;
  Ql[i] = (_Float16)r;
}

__device__ inline unsigned pk2(_Float16 a, _Float16 b) {
  union { _Float16 h[2]; unsigned u; } p;
  p.h[0] = a; p.h[1] = b;
  return p.u;
}

__global__ __launch_bounds__(256, 8) void sparse_att_kernel(
    const float* __restrict__ x,      // (B,128,64)
    const _Float16* __restrict__ Qh,  // (64,64) fp16 hi of 0.5*Q
    const _Float16* __restrict__ Ql,  // (64,64) fp16 lo of 0.5*Q
    const float* __restrict__ vals,   // (64,128)
    float* __restrict__ out)          // (B,64,128)
{
  // 16KB LDS, time-shared: phase 1 = x[b] as fp16 (swizzled, MFMA tile),
  // phase 2 = output transpose staging (2 passes of 64x64 f32).
  __shared__ __align__(16) unsigned char ldsbuf[16384];
  _Float16* xh = (_Float16*)ldsbuf;

  const int b   = blockIdx.x;
  const int tid = threadIdx.x;
  const int l   = tid & 63;
  const int otile = tid >> 6;         // wave id 0..3 -> o-tile
  const int lc  = l & 15;             // A-row within tile / C-col (o)
  const int fq  = l >> 4;             // k-block selector / C row-quad
  const int o   = otile * 16 + lc;    // this lane's output o (C layout)

  // ---- stage x[b] -> LDS fp16 hi, swizzled ----
  {
    const float4* xg = (const float4*)(x + (size_t)b * 8192);
    #pragma unroll
    for (int k = 0; k < 8; ++k) {
      int j = tid + k * 256;          // float4 index 0..2047
      int f = j >> 4, c = j & 15;
      float4 v = xg[j];
      _Float16 h0 = (_Float16)v.x, h1 = (_Float16)v.y,
               h2 = (_Float16)v.z, h3 = (_Float16)v.w;
      int byteoff = f * 128 + (((c >> 1) ^ (f & 7)) * 16) + (c & 1) * 8;
      uint2 uh; uh.x = pk2(h0, h1); uh.y = pk2(h2, h3);
      *(uint2*)((char*)xh + byteoff) = uh;
    }
  }

  // ---- B fragments (0.5*Q hi/lo) straight from global (L2-hot, 16KB) ----
  half8 bh0 = *(const half8*)(Qh + o * 64 + 0 * 32 + fq * 8);
  half8 bh1 = *(const half8*)(Qh + o * 64 + 1 * 32 + fq * 8);
  half8 bl0 = *(const half8*)(Ql + o * 64 + 0 * 32 + fq * 8);
  half8 bl1 = *(const half8*)(Ql + o * 64 + 1 * 32 + fq * 8);

  __syncthreads();

  // ---- GEMM: C[f][o] tiles via mfma_f32_16x16x32_f16, 2-product split ----
  floatx4 acc[8];
  #pragma unroll
  for (int t = 0; t < 8; ++t) acc[t] = (floatx4)0.0f;

  #pragma unroll
  for (int ks = 0; ks < 2; ++ks) {
    half8 bh = ks ? bh1 : bh0;
    half8 bl = ks ? bl1 : bl0;
    #pragma unroll
    for (int ft = 0; ft < 8; ++ft) {
      int f = ft * 16 + lc;                    // A-row for this lane
      int blk = (ks * 4 + fq) ^ (f & 7);
      int byteoff = f * 128 + blk * 16;
      half8 ah = *(const half8*)((const char*)xh + byteoff);
      acc[ft] = __builtin_amdgcn_mfma_f32_16x16x32_f16(ah, bh, acc[ft], 0, 0, 0);
      acc[ft] = __builtin_amdgcn_mfma_f32_16x16x32_f16(ah, bl, acc[ft], 0, 0, 0);
    }
  }

  // ---- att = Xs (0.5 folded into Q); lane's f for acc[t][j] = t*16+fq*4+j
  float* att = (float*)acc;                    // 32 floats, static indexing

  // ---- row max over 128 f (4 lanes: xor 16, 32) ----
  float m = att[0];
  #pragma unroll
  for (int i = 1; i < 32; ++i) m = fmaxf(m, att[i]);
  m = fmaxf(m, __shfl_xor(m, 16));
  m = fmaxf(m, __shfl_xor(m, 32));

  // ---- bisection (keeps f(tau) >= 0 invariant) ----
  float tau = m - 1.0f;
  float dm  = 0.91161165235168155f;       // 1 - (1/128)^0.5
  #pragma unroll
  for (int it = 0; it < NBIS; ++it) {
    dm *= 0.5f;
    float tm = tau + dm;
    float s0 = 0.f, s1 = 0.f, s2 = 0.f, s3 = 0.f;
    #pragma unroll
    for (int i = 0; i < 32; i += 4) {
      float t0 = fmaxf(att[i + 0] - tm, 0.0f);
      float t1 = fmaxf(att[i + 1] - tm, 0.0f);
      float t2 = fmaxf(att[i + 2] - tm, 0.0f);
      float t3 = fmaxf(att[i + 3] - tm, 0.0f);
      s0 = fmaf(t0, t0, s0); s1 = fmaf(t1, t1, s1);
      s2 = fmaf(t2, t2, s2); s3 = fmaf(t3, t3, s3);
    }
    float s = (s0 + s1) + (s2 + s3);
    s += __shfl_xor(s, 16);
    s += __shfl_xor(s, 32);
    tau = (s >= 1.0f) ? tm : tau;
  }

  // ---- Newton (monotone from f>=0 side; f convex, never overshoots) ----
  #pragma unroll
  for (int it = 0; it < NNEWT; ++it) {
    float s0 = 0.f, s1 = 0.f, d0 = 0.f, d1 = 0.f;
    #pragma unroll
    for (int i = 0; i < 32; i += 2) {
      float t0 = fmaxf(att[i + 0] - tau, 0.0f);
      float t1 = fmaxf(att[i + 1] - tau, 0.0f);
      s0 = fmaf(t0, t0, s0); d0 += t0;
      s1 = fmaf(t1, t1, s1); d1 += t1;
    }
    float s = s0 + s1, d = d0 + d1;
    s += __shfl_xor(s, 16);  d += __shfl_xor(d, 16);
    s += __shfl_xor(s, 32);  d += __shfl_xor(d, 32);
    tau += (s - 1.0f) / (2.0f * d);
  }

  // ---- final p and sum ----
  float s0 = 0.f, s1 = 0.f;
  #pragma unroll
  for (int i = 0; i < 32; ++i) {
    float t = fmaxf(att[i] - tau, 0.0f);
    float p = t * t;
    att[i] = p;
    if (i & 1) s1 += p; else s0 += p;
  }
  float s = s0 + s1;
  s += __shfl_xor(s, 16);
  s += __shfl_xor(s, 32);
  float inv = 1.0f / s;

  // ---- epilogue: p*inv*vals, transposed through LDS, coalesced NT store
  const float4* vg = (const float4*)(vals + o * 128);
  #pragma unroll
  for (int pass = 0; pass < 2; ++pass) {
    __syncthreads();   // pass0: all waves done reading x-tile; pass1: pass0 reads done
    #pragma unroll
    for (int t = 0; t < 4; ++t) {
      int ft = pass * 4 + t;
      float4 vv = vg[ft * 4 + fq];           // vals[o][ft*16+fq*4 .. +3]
      floatx4 r;
      r.x = att[ft * 4 + 0] * inv * vv.x;
      r.y = att[ft * 4 + 1] * inv * vv.y;
      r.z = att[ft * 4 + 2] * inv * vv.z;
      r.w = att[ft * 4 + 3] * inv * vv.w;
      int fr = ft * 16 + fq * 4 - pass * 64; // 0..63 f-local to this pass
      int off = (o * 256 + fr * 4) ^ ((o & 7) << 4);
      *(floatx4*)(ldsbuf + off) = r;
    }
    __syncthreads();
    #pragma unroll
    for (int k = 0; k < 4; ++k) {
      int j = tid + k * 256;                 // float4 index 0..1023
      int oo = j >> 4, f4 = j & 15;
      int off = (oo * 256 + f4 * 16) ^ ((oo & 7) << 4);
      floatx4 r = *(const floatx4*)(ldsbuf + off);
      __builtin_nontemporal_store(
          r, (floatx4*)(out + ((size_t)b * 64 + oo) * 128 + pass * 64 + f4 * 4));
    }
  }
}

extern "C" void kernel_launch(void* const* d_in, const int* in_sizes, int n_in,
                              void* d_out, int out_size, void* d_ws, size_t ws_size,
                              hipStream_t stream) {
  const float* x  = (const float*)d_in[0];
  const float* Qf = (const float*)d_in[1];
  const float* v  = (const float*)d_in[2];
  float* out = (float*)d_out;

  _Float16* Qh = (_Float16*)d_ws;            // 4096 halves = 8KB
  _Float16* Ql = Qh + 4096;                  // next 8KB

  hipLaunchKernelGGL(convert_q_kernel, dim3(16), dim3(256), 0, stream, Qf, Qh, Ql);
  hipLaunchKernelGGL(sparse_att_kernel, dim3(Bn), dim3(256), 0, stream,
                     x, Qh, Ql, v, out);
}